// Round 9
// baseline (201.830 us; speedup 1.0000x reference)
//
#include <hip/hip_runtime.h>

#define NCC_EPS 1.1920929e-07f

// ===========================================================================
// Scale-0 NCC without a padded volume: branchless loads via per-thread
// pointer selection (computed once): W-edge threads read from thin pre-padded
// edge strips [b][z][h][16]; H-OOB rows and D-OOB slices redirect to a zero
// buffer via cndmask on the base pointer. Hot loop identical to round 8:
// register W-sliding sums, LDS wb (conflict-free), parity double-buffer,
// clobber-free lgkmcnt(0)+s_barrier seam so the z+1 register prefetch's
// vmcnt stays in flight across the barrier (T14).
// ===========================================================================
template<int WIN>
__global__ __launch_bounds__(256)
void ncc_strip_kernel(const float* __restrict__ I, const float* __restrict__ J,
                      const float* __restrict__ SLI, const float* __restrict__ SRI,
                      const float* __restrict__ SLJ, const float* __restrict__ SRJ,
                      const float* __restrict__ zerobuf,
                      int D, int H, int W,
                      int tilesH, int tilesW, int chunksD, int chunkLen,
                      double* __restrict__ acc)
{
    constexpr int RAD  = WIN / 2;
    constexpr int TH = 16, TW = 16;
    constexpr int WROWS = TH + 2 * RAD;
    constexpr int PSTR = 68;
    constexpr int QSTR = 24;
    constexpr int OFF  = 4 - RAD;
    constexpr int NWT  = WROWS * 4;
    constexpr float invV = 1.0f / (float)(WIN * WIN * WIN);

    __shared__ __align__(16) float wb0123[2][WROWS * PSTR];
    __shared__ __align__(16) float wb4[2][WROWS * QSTR];
    __shared__ float red[4];

    int bid = blockIdx.x;
    int tw = bid % tilesW; bid /= tilesW;
    int th = bid % tilesH; bid /= tilesH;
    int cd = bid % chunksD; bid /= chunksD;
    int b  = bid;

    const int h0 = th * TH, w0 = tw * TW;
    const int z0 = cd * chunkLen;
    const int z1 = min(z0 + chunkLen, D);

    const size_t plane = (size_t)H * W;

    const int t  = threadIdx.x;
    const int hh = t >> 4, ww = t & 15;
    const bool valid = (w0 + ww) < W;

    const int wr  = t >> 2;
    const int wc4 = t & 3;
    const bool wact = t < NWT;
    const int wbase = w0 + 4 * wc4 - 4;
    const int wghr  = h0 + wr - RAD;

    // ---- per-thread source select (once): main / stripL / stripR / zero ----
    const float *bI, *bJ;
    long pstr;
    const bool rowOOB = (wghr < 0) || (wghr >= H);
    if (!wact || rowOOB) {
        bI = zerobuf; bJ = zerobuf; pstr = 0;
    } else if (wbase < 0) {
        size_t off = ((size_t)b * D * H + (size_t)wghr) * 16 + (wbase + 4);
        bI = SLI + off; bJ = SLJ + off; pstr = (long)H * 16;
    } else if (wbase + 12 > W) {
        size_t off = ((size_t)b * D * H + (size_t)wghr) * 16 + (wbase - (W - 12));
        bI = SRI + off; bJ = SRJ + off; pstr = (long)H * 16;
    } else {
        size_t off = (size_t)b * D * plane + (size_t)wghr * W + wbase;
        bI = I + off; bJ = J + off; pstr = (long)plane;
    }

    auto load_slice = [&](int z, float (&fi)[12], float (&fj)[12]) {
        if (wact) {
            const bool zok = (z >= 0) && (z < D);
            const float* pI = zok ? (bI + (size_t)((long)z * pstr)) : zerobuf;
            const float* pJ = zok ? (bJ + (size_t)((long)z * pstr)) : zerobuf;
            float4 a0 = *reinterpret_cast<const float4*>(pI);
            float4 a1 = *reinterpret_cast<const float4*>(pI + 4);
            float4 a2 = *reinterpret_cast<const float4*>(pI + 8);
            float4 b0 = *reinterpret_cast<const float4*>(pJ);
            float4 b1 = *reinterpret_cast<const float4*>(pJ + 4);
            float4 b2 = *reinterpret_cast<const float4*>(pJ + 8);
            fi[0]=a0.x; fi[1]=a0.y; fi[2]=a0.z; fi[3]=a0.w;
            fi[4]=a1.x; fi[5]=a1.y; fi[6]=a1.z; fi[7]=a1.w;
            fi[8]=a2.x; fi[9]=a2.y; fi[10]=a2.z; fi[11]=a2.w;
            fj[0]=b0.x; fj[1]=b0.y; fj[2]=b0.z; fj[3]=b0.w;
            fj[4]=b1.x; fj[5]=b1.y; fj[6]=b1.z; fj[7]=b1.w;
            fj[8]=b2.x; fj[9]=b2.y; fj[10]=b2.z; fj[11]=b2.w;
        }
    };

    float ring[WIN][5];
    float rs[5];
    #pragma unroll
    for (int s = 0; s < WIN; ++s)
        #pragma unroll
        for (int c = 0; c < 5; ++c) ring[s][c] = 0.f;
    #pragma unroll
    for (int c = 0; c < 5; ++c) rs[c] = 0.f;

    float ccsum = 0.f;

    float fiC[12], fjC[12], fiN[12], fjN[12];
    const int zend = z1 + RAD;
    load_slice(z0 - RAD, fiC, fjC);

    for (int zb = z0 - RAD; zb < zend; zb += WIN) {
        #pragma unroll
        for (int ph = 0; ph < WIN; ++ph) {
            const int z = zb + ph;                 // uniform across block
            if (z < zend) {
                // ---- 1) prefetch slice z+1 ----
                load_slice(z + 1, fiN, fjN);

                const int par = (z + 8) & 1;       // uniform parity
                float n0, n1, n2, n3, n4;
                // ---- 2) W phase ----
                if (wact) {
                    float s0 = 0, s1 = 0, s2 = 0, s3 = 0, s4 = 0;
                    #pragma unroll
                    for (int k = 0; k < WIN; ++k) {
                        float a = fiC[OFF + k], bb = fjC[OFF + k];
                        s0 += a; s1 += bb;
                        s2 = fmaf(a, a, s2);
                        s3 = fmaf(bb, bb, s3);
                        s4 = fmaf(a, bb, s4);
                    }
                    float o0[4], o1[4], o2[4], o3[4], o4[4];
                    o0[0]=s0; o1[0]=s1; o2[0]=s2; o3[0]=s3; o4[0]=s4;
                    #pragma unroll
                    for (int m = 1; m < 4; ++m) {
                        float aL = fiC[OFF + m - 1],       bL = fjC[OFF + m - 1];
                        float aR = fiC[OFF + m - 1 + WIN], bR = fjC[OFF + m - 1 + WIN];
                        s0 += aR - aL;
                        s1 += bR - bL;
                        s2 = s2 + aR * aR - aL * aL;
                        s3 = s3 + bR * bR - bL * bL;
                        s4 = s4 + aR * bR - aL * bL;
                        o0[m]=s0; o1[m]=s1; o2[m]=s2; o3[m]=s3; o4[m]=s4;
                    }
                    #pragma unroll
                    for (int m = 0; m < 4; ++m) {
                        *reinterpret_cast<float4*>(&wb0123[par][wr * PSTR + 16 * wc4 + 4 * m]) =
                            make_float4(o0[m], o1[m], o2[m], o3[m]);
                    }
                    *reinterpret_cast<float4*>(&wb4[par][wr * QSTR + 4 * wc4]) =
                        make_float4(o4[0], o4[1], o4[2], o4[3]);
                }
                // ---- clobber-free barrier: vmcnt stays in flight ----
                __builtin_amdgcn_sched_barrier(0);
                asm volatile("s_waitcnt lgkmcnt(0)");
                __builtin_amdgcn_s_barrier();
                __builtin_amdgcn_sched_barrier(0);
                // ---- 3) H phase ----
                {
                    float4 a4 = make_float4(0.f, 0.f, 0.f, 0.f);
                    float nn4 = 0.f;
                    #pragma unroll
                    for (int dh = 0; dh < WIN; ++dh) {
                        float4 v = *reinterpret_cast<const float4*>(
                            &wb0123[par][(hh + dh) * PSTR + 4 * ww]);
                        a4.x += v.x; a4.y += v.y; a4.z += v.z; a4.w += v.w;
                        nn4 += wb4[par][(hh + dh) * QSTR + ww];
                    }
                    n0 = a4.x; n1 = a4.y; n2 = a4.z; n3 = a4.w; n4 = nn4;
                }
                // ---- 4) ring update ----
                rs[0] += n0 - ring[ph][0]; ring[ph][0] = n0;
                rs[1] += n1 - ring[ph][1]; ring[ph][1] = n1;
                rs[2] += n2 - ring[ph][2]; ring[ph][2] = n2;
                rs[3] += n3 - ring[ph][3]; ring[ph][3] = n3;
                rs[4] += n4 - ring[ph][4]; ring[ph][4] = n4;

                // ---- 5) emit ----
                const int zo = z - RAD;
                if (valid && zo >= z0) {
                    float muI = rs[0] * invV;
                    float muJ = rs[1] * invV;
                    float sII = rs[2] * invV - muI * muI;
                    float sJJ = rs[3] * invV - muJ * muJ;
                    float s12 = rs[4] * invV - muI * muJ;
                    float cc = (s12 * s12) / fmaxf(sII * sJJ, NCC_EPS);
                    ccsum += cc;
                }
                // ---- 6) rotate prefetch regs ----
                #pragma unroll
                for (int e = 0; e < 12; ++e) { fiC[e] = fiN[e]; fjC[e] = fjN[e]; }
            }
        }
    }

    for (int off = 32; off > 0; off >>= 1)
        ccsum += __shfl_down(ccsum, off);
    const int wid = t >> 6, lane = t & 63;
    if (lane == 0) red[wid] = ccsum;
    __syncthreads();
    if (t == 0) {
        float s = red[0] + red[1] + red[2] + red[3];
        atomicAdd(acc, (double)s);
    }
}

// Fill W-edge strips: SL covers cols [-4,11], SR covers cols [W-12, W+3],
// each stored as [b][z][h][16] with zeros outside [0,W).
__global__ void strip_fill(const float* __restrict__ I, const float* __restrict__ J,
                           float* __restrict__ SLI, float* __restrict__ SRI,
                           float* __restrict__ SLJ, float* __restrict__ SRJ,
                           int D, int H, int W, int N1)
{
    int idx = blockIdx.x * 256 + threadIdx.x;
    if (idx >= 4 * N1) return;
    int bufid = idx / N1;
    int r = idx - bufid * N1;
    int c4 = r & 3; r >>= 2;
    int h = r % H; int zb = r / H;              // zb = b*D + z

    const float* in = (bufid >= 2) ? J : I;
    float* out = (bufid == 0) ? SLI : (bufid == 1) ? SRI : (bufid == 2) ? SLJ : SRJ;
    const bool right = bufid & 1;
    const int c0 = 4 * c4 + (right ? (W - 12) : -4);

    float4 v = make_float4(0.f, 0.f, 0.f, 0.f);
    if (c0 >= 0 && c0 + 4 <= W)
        v = *reinterpret_cast<const float4*>(in + ((size_t)zb * H + h) * W + c0);
    *reinterpret_cast<float4*>(out + ((size_t)zb * H + h) * 16 + 4 * c4) = v;
}

// ===========================================================================
// Padded-pyramid NCC for scales 1/2 (inputs pre-padded by 4, zeros).
// ===========================================================================
template<int WIN>
__global__ __launch_bounds__(256)
void ncc_pad_kernel(const float* __restrict__ Pi, const float* __restrict__ Pj,
                    int Dp, int Hp, int Wp, int Dreal, int Wreal,
                    int tilesH, int tilesW, int chunksD, int chunkLen,
                    double* __restrict__ acc)
{
    constexpr int RAD  = WIN / 2;
    constexpr int TH = 16, TW = 16;
    constexpr int WROWS = TH + 2 * RAD;
    constexpr int PSTR = 68;
    constexpr int QSTR = 24;
    constexpr int OFF  = 4 - RAD;
    constexpr int NWT  = WROWS * 4;
    constexpr float invV = 1.0f / (float)(WIN * WIN * WIN);

    __shared__ __align__(16) float wb0123[2][WROWS * PSTR];
    __shared__ __align__(16) float wb4[2][WROWS * QSTR];
    __shared__ float red[4];

    int bid = blockIdx.x;
    int tw = bid % tilesW; bid /= tilesW;
    int th = bid % tilesH; bid /= tilesH;
    int cd = bid % chunksD; bid /= chunksD;
    int b  = bid;

    const int h0 = th * TH, w0 = tw * TW;
    const int z0 = cd * chunkLen;
    const int z1 = min(z0 + chunkLen, Dreal);

    const size_t plane = (size_t)Hp * Wp;
    const float* Ib = Pi + (size_t)b * Dp * plane;
    const float* Jb = Pj + (size_t)b * Dp * plane;

    const int t  = threadIdx.x;
    const int hh = t >> 4, ww = t & 15;
    const bool valid = (w0 + ww) < Wreal;

    const int wr  = t >> 2;
    const int wc4 = t & 3;
    const bool wact = t < NWT;
    const size_t rowoff = (size_t)(h0 + wr) * Wp + (w0 + 4 * wc4);

    auto load_slice = [&](int zp, float (&fi)[12], float (&fj)[12]) {
        if (wact) {
            const float* rI = Ib + (size_t)zp * plane + rowoff;
            const float* rJ = Jb + (size_t)zp * plane + rowoff;
            float4 a0 = *reinterpret_cast<const float4*>(rI);
            float4 a1 = *reinterpret_cast<const float4*>(rI + 4);
            float4 a2 = *reinterpret_cast<const float4*>(rI + 8);
            float4 b0 = *reinterpret_cast<const float4*>(rJ);
            float4 b1 = *reinterpret_cast<const float4*>(rJ + 4);
            float4 b2 = *reinterpret_cast<const float4*>(rJ + 8);
            fi[0]=a0.x; fi[1]=a0.y; fi[2]=a0.z; fi[3]=a0.w;
            fi[4]=a1.x; fi[5]=a1.y; fi[6]=a1.z; fi[7]=a1.w;
            fi[8]=a2.x; fi[9]=a2.y; fi[10]=a2.z; fi[11]=a2.w;
            fj[0]=b0.x; fj[1]=b0.y; fj[2]=b0.z; fj[3]=b0.w;
            fj[4]=b1.x; fj[5]=b1.y; fj[6]=b1.z; fj[7]=b1.w;
            fj[8]=b2.x; fj[9]=b2.y; fj[10]=b2.z; fj[11]=b2.w;
        }
    };

    float ring[WIN][5];
    float rs[5];
    #pragma unroll
    for (int s = 0; s < WIN; ++s)
        #pragma unroll
        for (int c = 0; c < 5; ++c) ring[s][c] = 0.f;
    #pragma unroll
    for (int c = 0; c < 5; ++c) rs[c] = 0.f;

    float ccsum = 0.f;

    float fiC[12], fjC[12], fiN[12], fjN[12];
    const int zend = z1 + RAD;
    load_slice(z0 - RAD + 4, fiC, fjC);

    for (int zb = z0 - RAD; zb < zend; zb += WIN) {
        #pragma unroll
        for (int ph = 0; ph < WIN; ++ph) {
            const int z = zb + ph;
            if (z < zend) {
                const int zpn = min(z + 5, Dp - 1);
                load_slice(zpn, fiN, fjN);

                const int par = (z + 4) & 1;
                float n0, n1, n2, n3, n4;
                if (wact) {
                    float s0 = 0, s1 = 0, s2 = 0, s3 = 0, s4 = 0;
                    #pragma unroll
                    for (int k = 0; k < WIN; ++k) {
                        float a = fiC[OFF + k], bb = fjC[OFF + k];
                        s0 += a; s1 += bb;
                        s2 = fmaf(a, a, s2);
                        s3 = fmaf(bb, bb, s3);
                        s4 = fmaf(a, bb, s4);
                    }
                    float o0[4], o1[4], o2[4], o3[4], o4[4];
                    o0[0]=s0; o1[0]=s1; o2[0]=s2; o3[0]=s3; o4[0]=s4;
                    #pragma unroll
                    for (int m = 1; m < 4; ++m) {
                        float aL = fiC[OFF + m - 1],       bL = fjC[OFF + m - 1];
                        float aR = fiC[OFF + m - 1 + WIN], bR = fjC[OFF + m - 1 + WIN];
                        s0 += aR - aL;
                        s1 += bR - bL;
                        s2 = s2 + aR * aR - aL * aL;
                        s3 = s3 + bR * bR - bL * bL;
                        s4 = s4 + aR * bR - aL * bL;
                        o0[m]=s0; o1[m]=s1; o2[m]=s2; o3[m]=s3; o4[m]=s4;
                    }
                    #pragma unroll
                    for (int m = 0; m < 4; ++m) {
                        *reinterpret_cast<float4*>(&wb0123[par][wr * PSTR + 16 * wc4 + 4 * m]) =
                            make_float4(o0[m], o1[m], o2[m], o3[m]);
                    }
                    *reinterpret_cast<float4*>(&wb4[par][wr * QSTR + 4 * wc4]) =
                        make_float4(o4[0], o4[1], o4[2], o4[3]);
                }
                __builtin_amdgcn_sched_barrier(0);
                asm volatile("s_waitcnt lgkmcnt(0)");
                __builtin_amdgcn_s_barrier();
                __builtin_amdgcn_sched_barrier(0);
                {
                    float4 a4 = make_float4(0.f, 0.f, 0.f, 0.f);
                    float nn4 = 0.f;
                    #pragma unroll
                    for (int dh = 0; dh < WIN; ++dh) {
                        float4 v = *reinterpret_cast<const float4*>(
                            &wb0123[par][(hh + dh) * PSTR + 4 * ww]);
                        a4.x += v.x; a4.y += v.y; a4.z += v.z; a4.w += v.w;
                        nn4 += wb4[par][(hh + dh) * QSTR + ww];
                    }
                    n0 = a4.x; n1 = a4.y; n2 = a4.z; n3 = a4.w; n4 = nn4;
                }
                rs[0] += n0 - ring[ph][0]; ring[ph][0] = n0;
                rs[1] += n1 - ring[ph][1]; ring[ph][1] = n1;
                rs[2] += n2 - ring[ph][2]; ring[ph][2] = n2;
                rs[3] += n3 - ring[ph][3]; ring[ph][3] = n3;
                rs[4] += n4 - ring[ph][4]; ring[ph][4] = n4;

                const int zo = z - RAD;
                if (valid && zo >= z0) {
                    float muI = rs[0] * invV;
                    float muJ = rs[1] * invV;
                    float sII = rs[2] * invV - muI * muI;
                    float sJJ = rs[3] * invV - muJ * muJ;
                    float s12 = rs[4] * invV - muI * muJ;
                    float cc = (s12 * s12) / fmaxf(sII * sJJ, NCC_EPS);
                    ccsum += cc;
                }
                #pragma unroll
                for (int e = 0; e < 12; ++e) { fiC[e] = fiN[e]; fjC[e] = fjN[e]; }
            }
        }
    }

    for (int off = 32; off > 0; off >>= 1)
        ccsum += __shfl_down(ccsum, off);
    const int wid = t >> 6, lane = t & 63;
    if (lane == 0) red[wid] = ccsum;
    __syncthreads();
    if (t == 0) {
        float s = red[0] + red[1] + red[2] + red[3];
        atomicAdd(acc, (double)s);
    }
}

// avg_pool3d from UNPADDED source -> padded destination (interior only).
__global__ void pool_b2p_kernel(const float* __restrict__ inA, const float* __restrict__ inB,
                                float* __restrict__ outA, float* __restrict__ outB,
                                int D, int H, int W, int oD, int oH, int oW,
                                int oDp, int oHp, int oWp, int total)
{
    int idx0 = blockIdx.x * 256 + threadIdx.x;
    if (idx0 >= 2 * total) return;
    const bool isB = idx0 >= total;
    int idx = isB ? idx0 - total : idx0;
    const float* in = isB ? inB : inA;
    float* out = isB ? outB : outA;

    int ow = idx % oW; int tmp = idx / oW;
    int oh = tmp % oH; tmp /= oH;
    int od = tmp % oD; int b = tmp / oD;

    int dlo = max(2 * od - 1, 0), dhi = min(2 * od + 2, D);
    int hlo = max(2 * oh - 1, 0), hhi = min(2 * oh + 2, H);
    int wlo = max(2 * ow - 1, 0), whi = min(2 * ow + 2, W);

    const float* ib = in + (size_t)b * D * H * W;
    float s = 0.f;
    for (int d = dlo; d < dhi; ++d)
        for (int h = hlo; h < hhi; ++h)
            for (int w = wlo; w < whi; ++w)
                s += ib[((size_t)d * H + h) * W + w];
    int cnt = (dhi - dlo) * (hhi - hlo) * (whi - wlo);
    out[((size_t)(b * oDp + od + 4) * oHp + (oh + 4)) * oWp + (ow + 4)] = s / (float)cnt;
}

// avg_pool3d padded source -> padded destination (interior only).
__global__ void pool_pad_kernel(const float* __restrict__ inA, const float* __restrict__ inB,
                                float* __restrict__ outA, float* __restrict__ outB,
                                int D, int H, int W, int iDp, int iHp, int iWp,
                                int oD, int oH, int oW, int oDp, int oHp, int oWp,
                                int total)
{
    int idx0 = blockIdx.x * 256 + threadIdx.x;
    if (idx0 >= 2 * total) return;
    const bool isB = idx0 >= total;
    int idx = isB ? idx0 - total : idx0;
    const float* in = isB ? inB : inA;
    float* out = isB ? outB : outA;

    int ow = idx % oW; int tmp = idx / oW;
    int oh = tmp % oH; tmp /= oH;
    int od = tmp % oD; int b = tmp / oD;

    const size_t ip = (size_t)iHp * iWp;
    const float* ib = in + (size_t)b * iDp * ip;
    float s = 0.f;
    #pragma unroll
    for (int dd = 0; dd < 3; ++dd)
        #pragma unroll
        for (int dh = 0; dh < 3; ++dh) {
            const float* r = ib + (size_t)(2 * od + 3 + dd) * ip
                                + (size_t)(2 * oh + 3 + dh) * iWp + (2 * ow + 3);
            s += r[0]; s += r[1]; s += r[2];
        }
    int dlo = max(2 * od - 1, 0), dhi = min(2 * od + 2, D);
    int hlo = max(2 * oh - 1, 0), hhi = min(2 * oh + 2, H);
    int wlo = max(2 * ow - 1, 0), whi = min(2 * ow + 2, W);
    int cnt = (dhi - dlo) * (hhi - hlo) * (whi - wlo);
    out[((size_t)(b * oDp + od + 4) * oHp + (oh + 4)) * oWp + (ow + 4)] = s / (float)cnt;
}

// ===========================================================================
// FALLBACK PATH (small workspace): bounded kernel, verified passing.
// ===========================================================================
template<int WIN>
__global__ __launch_bounds__(256)
void ncc_scale_kernel(const float* __restrict__ I, const float* __restrict__ J,
                      int D, int H, int W,
                      int tilesH, int tilesW, int chunksD, int chunkLen,
                      double* __restrict__ acc)
{
    constexpr int RAD  = WIN / 2;
    constexpr int TH = 16, TW = 16;
    constexpr int WROWS = TH + 2 * RAD;
    constexpr int PSTR = 68;
    constexpr int QSTR = 24;
    constexpr int OFF  = 4 - RAD;
    constexpr int NWT  = WROWS * 4;
    constexpr float invV = 1.0f / (float)(WIN * WIN * WIN);

    __shared__ __align__(16) float wb0123[2][WROWS * PSTR];
    __shared__ __align__(16) float wb4[2][WROWS * QSTR];
    __shared__ float red[4];

    int bid = blockIdx.x;
    int tw = bid % tilesW; bid /= tilesW;
    int th = bid % tilesH; bid /= tilesH;
    int cd = bid % chunksD; bid /= chunksD;
    int b  = bid;

    const int h0 = th * TH, w0 = tw * TW;
    const int z0 = cd * chunkLen;
    const int z1 = min(z0 + chunkLen, D);

    const size_t plane = (size_t)H * W;
    const float* Ib = I + (size_t)b * D * plane;
    const float* Jb = J + (size_t)b * D * plane;

    const int t  = threadIdx.x;
    const int hh = t >> 4, ww = t & 15;
    const int gh = h0 + hh, gw = w0 + ww;
    const bool valid = (gh < H) && (gw < W);

    const int wr  = t >> 2;
    const int wc4 = t & 3;
    const bool wact = t < NWT;
    const int wbase = w0 + 4 * wc4 - 4;
    const int wghr  = h0 + wr - RAD;

    auto load_slice = [&](int z, float (&fi)[12], float (&fj)[12]) {
        const bool zok = (z >= 0) && (z < D);
        if (zok && wact && wghr >= 0 && wghr < H) {
            const float* rowI = Ib + (size_t)z * plane + (size_t)wghr * W;
            const float* rowJ = Jb + (size_t)z * plane + (size_t)wghr * W;
            if (wbase >= 0 && wbase + 12 <= W) {
                float4 a0 = *reinterpret_cast<const float4*>(rowI + wbase);
                float4 a1 = *reinterpret_cast<const float4*>(rowI + wbase + 4);
                float4 a2 = *reinterpret_cast<const float4*>(rowI + wbase + 8);
                float4 b0 = *reinterpret_cast<const float4*>(rowJ + wbase);
                float4 b1 = *reinterpret_cast<const float4*>(rowJ + wbase + 4);
                float4 b2 = *reinterpret_cast<const float4*>(rowJ + wbase + 8);
                fi[0]=a0.x; fi[1]=a0.y; fi[2]=a0.z; fi[3]=a0.w;
                fi[4]=a1.x; fi[5]=a1.y; fi[6]=a1.z; fi[7]=a1.w;
                fi[8]=a2.x; fi[9]=a2.y; fi[10]=a2.z; fi[11]=a2.w;
                fj[0]=b0.x; fj[1]=b0.y; fj[2]=b0.z; fj[3]=b0.w;
                fj[4]=b1.x; fj[5]=b1.y; fj[6]=b1.z; fj[7]=b1.w;
                fj[8]=b2.x; fj[9]=b2.y; fj[10]=b2.z; fj[11]=b2.w;
            } else {
                #pragma unroll
                for (int e = 0; e < 12; ++e) {
                    int cg = wbase + e;
                    bool ok = (cg >= 0) && (cg < W);
                    fi[e] = ok ? rowI[cg] : 0.f;
                    fj[e] = ok ? rowJ[cg] : 0.f;
                }
            }
        } else {
            #pragma unroll
            for (int e = 0; e < 12; ++e) { fi[e] = 0.f; fj[e] = 0.f; }
        }
    };

    float ring[WIN][5];
    float rs[5];
    #pragma unroll
    for (int s = 0; s < WIN; ++s)
        #pragma unroll
        for (int c = 0; c < 5; ++c) ring[s][c] = 0.f;
    #pragma unroll
    for (int c = 0; c < 5; ++c) rs[c] = 0.f;

    float ccsum = 0.f;

    float fiC[12], fjC[12], fiN[12], fjN[12];
    const int zend = z1 + RAD;
    load_slice(z0 - RAD, fiC, fjC);

    for (int zb = z0 - RAD; zb < zend; zb += WIN) {
        #pragma unroll
        for (int ph = 0; ph < WIN; ++ph) {
            const int z = zb + ph;
            if (z < zend) {
                const bool zin = (z >= 0) && (z < D);
                load_slice((z + 1 < zend) ? z + 1 : -1, fiN, fjN);
                float n0 = 0, n1 = 0, n2 = 0, n3 = 0, n4 = 0;
                if (zin) {
                    const int par = (z + 64) & 1;
                    if (wact) {
                        float s0 = 0, s1 = 0, s2 = 0, s3 = 0, s4 = 0;
                        #pragma unroll
                        for (int k = 0; k < WIN; ++k) {
                            float a = fiC[OFF + k], bb = fjC[OFF + k];
                            s0 += a; s1 += bb;
                            s2 = fmaf(a, a, s2);
                            s3 = fmaf(bb, bb, s3);
                            s4 = fmaf(a, bb, s4);
                        }
                        float o0[4], o1[4], o2[4], o3[4], o4[4];
                        o0[0]=s0; o1[0]=s1; o2[0]=s2; o3[0]=s3; o4[0]=s4;
                        #pragma unroll
                        for (int m = 1; m < 4; ++m) {
                            float aL = fiC[OFF + m - 1],       bL = fjC[OFF + m - 1];
                            float aR = fiC[OFF + m - 1 + WIN], bR = fjC[OFF + m - 1 + WIN];
                            s0 += aR - aL;
                            s1 += bR - bL;
                            s2 = s2 + aR * aR - aL * aL;
                            s3 = s3 + bR * bR - bL * bL;
                            s4 = s4 + aR * bR - aL * bL;
                            o0[m]=s0; o1[m]=s1; o2[m]=s2; o3[m]=s3; o4[m]=s4;
                        }
                        #pragma unroll
                        for (int m = 0; m < 4; ++m) {
                            *reinterpret_cast<float4*>(&wb0123[par][wr * PSTR + 16 * wc4 + 4 * m]) =
                                make_float4(o0[m], o1[m], o2[m], o3[m]);
                        }
                        *reinterpret_cast<float4*>(&wb4[par][wr * QSTR + 4 * wc4]) =
                            make_float4(o4[0], o4[1], o4[2], o4[3]);
                    }
                    __syncthreads();
                    float4 a4 = make_float4(0.f, 0.f, 0.f, 0.f);
                    #pragma unroll
                    for (int dh = 0; dh < WIN; ++dh) {
                        float4 v = *reinterpret_cast<const float4*>(
                            &wb0123[par][(hh + dh) * PSTR + 4 * ww]);
                        a4.x += v.x; a4.y += v.y; a4.z += v.z; a4.w += v.w;
                        n4 += wb4[par][(hh + dh) * QSTR + ww];
                    }
                    n0 = a4.x; n1 = a4.y; n2 = a4.z; n3 = a4.w;
                }
                rs[0] += n0 - ring[ph][0]; ring[ph][0] = n0;
                rs[1] += n1 - ring[ph][1]; ring[ph][1] = n1;
                rs[2] += n2 - ring[ph][2]; ring[ph][2] = n2;
                rs[3] += n3 - ring[ph][3]; ring[ph][3] = n3;
                rs[4] += n4 - ring[ph][4]; ring[ph][4] = n4;

                const int zo = z - RAD;
                if (valid && zo >= z0) {
                    float muI = rs[0] * invV;
                    float muJ = rs[1] * invV;
                    float sII = rs[2] * invV - muI * muI;
                    float sJJ = rs[3] * invV - muJ * muJ;
                    float s12 = rs[4] * invV - muI * muJ;
                    float cc = (s12 * s12) / fmaxf(sII * sJJ, NCC_EPS);
                    ccsum += cc;
                }
                #pragma unroll
                for (int e = 0; e < 12; ++e) { fiC[e] = fiN[e]; fjC[e] = fjN[e]; }
            }
        }
    }

    for (int off = 32; off > 0; off >>= 1)
        ccsum += __shfl_down(ccsum, off);
    const int wid = t >> 6, lane = t & 63;
    if (lane == 0) red[wid] = ccsum;
    __syncthreads();
    if (t == 0) {
        float s = red[0] + red[1] + red[2] + red[3];
        atomicAdd(acc, (double)s);
    }
}

__global__ void pool_kernel2(const float* __restrict__ inA, const float* __restrict__ inB,
                             float* __restrict__ outA, float* __restrict__ outB,
                             int D, int H, int W, int oD, int oH, int oW, int total)
{
    int idx0 = blockIdx.x * 256 + threadIdx.x;
    if (idx0 >= 2 * total) return;
    const bool isB = idx0 >= total;
    int idx = isB ? idx0 - total : idx0;
    const float* in = isB ? inB : inA;
    float* out = isB ? outB : outA;

    int ow = idx % oW; int tmp = idx / oW;
    int oh = tmp % oH; tmp /= oH;
    int od = tmp % oD; int b = tmp / oD;

    int dlo = max(2 * od - 1, 0), dhi = min(2 * od + 2, D);
    int hlo = max(2 * oh - 1, 0), hhi = min(2 * oh + 2, H);
    int wlo = max(2 * ow - 1, 0), whi = min(2 * ow + 2, W);

    const float* ib = in + (size_t)b * D * H * W;
    float s = 0.f;
    for (int d = dlo; d < dhi; ++d)
        for (int h = hlo; h < hhi; ++h)
            for (int w = wlo; w < whi; ++w)
                s += ib[((size_t)d * H + h) * W + w];
    int cnt = (dhi - dlo) * (hhi - hlo) * (whi - wlo);
    out[idx] = s / (float)cnt;
}

__global__ void finalize_kernel(const double* __restrict__ acc, float* __restrict__ out)
{
    double m = acc[0] / 9830400.0 + acc[1] / 1228800.0 + acc[2] / 153600.0;
    out[0] = (float)(-m / 3.0);
}

extern "C" void kernel_launch(void* const* d_in, const int* in_sizes, int n_in,
                              void* d_out, int out_size, void* d_ws, size_t ws_size,
                              hipStream_t stream)
{
    const float* I0 = (const float*)d_in[0];
    const float* J0 = (const float*)d_in[1];
    float* out = (float*)d_out;

    char* ws = (char*)d_ws;
    // layout: [0,192) zerobuf (48 floats) | [192,216) acc (3 doubles) | 256: strips...
    float* zerobuf = (float*)ws;
    double* acc = (double*)(ws + 192);

    const size_t SSZ  = (size_t)2 * 160 * 192 * 16;    // per strip buffer (983,040)
    const size_t P1SZ = (size_t)2 * 88 * 104 * 88;     // per array (1,610,752)
    const size_t P2SZ = (size_t)2 * 48 * 56 * 56;      // per array (301,056)
    const size_t need = 256 + (4 * SSZ + 2 * P1SZ + 2 * P2SZ) * sizeof(float);

    if (ws_size >= need) {
        float* SLI = (float*)(ws + 256);
        float* SRI = SLI + SSZ;
        float* SLJ = SRI + SSZ;
        float* SRJ = SLJ + SSZ;
        float* P1I = SRJ + SSZ;
        float* P1J = P1I + P1SZ;
        float* P2I = P1J + P1SZ;
        float* P2J = P2I + P2SZ;

        hipMemsetAsync(ws, 0, 256, stream);                       // zerobuf + acc
        hipMemsetAsync(P1I, 0, (2 * P1SZ + 2 * P2SZ) * sizeof(float), stream);

        // fill W-edge strips for scale 0
        {
            int N1 = 2 * 160 * 192 * 4;                           // chunks per buffer
            int blocks = (4 * N1 + 255) / 256;
            strip_fill<<<blocks, 256, 0, stream>>>(I0, J0, SLI, SRI, SLJ, SRJ,
                                                   160, 192, 160, N1);
        }
        // scale 0: win=9, reads original + strips
        ncc_strip_kernel<9><<<2 * 12 * 10 * 4, 256, 0, stream>>>(
            I0, J0, SLI, SRI, SLJ, SRJ, zerobuf,
            160, 192, 160, 12, 10, 4, 40, acc + 0);
        // pool 0 -> 1 (original -> padded P1)
        {
            int total = 2 * 80 * 96 * 80;
            int blocks = (2 * total + 255) / 256;
            pool_b2p_kernel<<<blocks, 256, 0, stream>>>(I0, J0, P1I, P1J,
                                                        160, 192, 160, 80, 96, 80,
                                                        88, 104, 88, total);
        }
        // scale 1: win=7 (padded)
        ncc_pad_kernel<7><<<2 * 6 * 5 * 4, 256, 0, stream>>>(
            P1I, P1J, 88, 104, 88, 80, 80, 6, 5, 4, 20, acc + 1);
        // pool 1 -> 2 (padded -> padded)
        {
            int total = 2 * 40 * 48 * 40;
            int blocks = (2 * total + 255) / 256;
            pool_pad_kernel<<<blocks, 256, 0, stream>>>(P1I, P1J, P2I, P2J,
                                                        80, 96, 80, 88, 104, 88,
                                                        40, 48, 40, 48, 56, 56, total);
        }
        // scale 2: win=5 (padded)
        ncc_pad_kernel<5><<<2 * 3 * 3 * 5, 256, 0, stream>>>(
            P2I, P2J, 48, 56, 56, 40, 40, 3, 3, 5, 8, acc + 2);
    } else {
        // ---------------- FALLBACK (bounded path) ----------------
        hipMemsetAsync(ws, 0, 256, stream);
        float* I1 = (float*)(ws + 256);
        float* J1 = I1 + (size_t)2 * 80 * 96 * 80;
        float* I2 = J1 + (size_t)2 * 80 * 96 * 80;
        float* J2 = I2 + (size_t)2 * 40 * 48 * 40;

        ncc_scale_kernel<9><<<2 * 12 * 10 * 4, 256, 0, stream>>>(
            I0, J0, 160, 192, 160, 12, 10, 4, 40, acc + 0);
        {
            int total = 2 * 80 * 96 * 80;
            int blocks = (2 * total + 255) / 256;
            pool_kernel2<<<blocks, 256, 0, stream>>>(I0, J0, I1, J1,
                                                     160, 192, 160, 80, 96, 80, total);
        }
        ncc_scale_kernel<7><<<2 * 6 * 5 * 8, 256, 0, stream>>>(
            I1, J1, 80, 96, 80, 6, 5, 8, 10, acc + 1);
        {
            int total = 2 * 40 * 48 * 40;
            int blocks = (2 * total + 255) / 256;
            pool_kernel2<<<blocks, 256, 0, stream>>>(I1, J1, I2, J2,
                                                     80, 96, 80, 40, 48, 40, total);
        }
        ncc_scale_kernel<5><<<2 * 3 * 3 * 14, 256, 0, stream>>>(
            I2, J2, 40, 48, 40, 3, 3, 14, 3, acc + 2);
    }

    finalize_kernel<<<1, 1, 0, stream>>>(acc, out);
}

// Round 10
// 184.583 us; speedup vs baseline: 1.0934x; 1.0934x over previous
//
#include <hip/hip_runtime.h>

#define NCC_EPS 1.1920929e-07f

// ===========================================================================
// PADDED PATH: all volumes padded by 4 on every face (zeros) in workspace,
// matching reference zero-padding. NCC kernel is fully branchless; slice z+1
// global loads are register-prefetched and stay in flight across a clobber-
// free lgkmcnt(0)+s_barrier seam (T14).
// LDS (lane-derived, conflict-free at the b128/2-way floor):
//   wb0123: float4/col, row stride 68; wb4: scalar, stride 24;
//   double-buffered by slice parity -> one barrier per slice.
// Round 10: grid sized to the 6-block/CU residency capacity (VGPR 80,
// LDS 17.9KB): scale0 chunksD=6 (1440 blocks), scale1 chunksD=10 (600).
// ===========================================================================
template<int WIN>
__global__ __launch_bounds__(256)
void ncc_pad_kernel(const float* __restrict__ Pi, const float* __restrict__ Pj,
                    int Dp, int Hp, int Wp, int Dreal, int Wreal,
                    int tilesH, int tilesW, int chunksD, int chunkLen,
                    double* __restrict__ acc)
{
    constexpr int RAD  = WIN / 2;
    constexpr int TH = 16, TW = 16;
    constexpr int WROWS = TH + 2 * RAD;
    constexpr int PSTR = 68;
    constexpr int QSTR = 24;
    constexpr int OFF  = 4 - RAD;
    constexpr int NWT  = WROWS * 4;
    constexpr float invV = 1.0f / (float)(WIN * WIN * WIN);

    __shared__ __align__(16) float wb0123[2][WROWS * PSTR];
    __shared__ __align__(16) float wb4[2][WROWS * QSTR];
    __shared__ float red[4];

    int bid = blockIdx.x;
    int tw = bid % tilesW; bid /= tilesW;
    int th = bid % tilesH; bid /= tilesH;
    int cd = bid % chunksD; bid /= chunksD;
    int b  = bid;

    const int h0 = th * TH, w0 = tw * TW;
    const int z0 = cd * chunkLen;
    const int z1 = min(z0 + chunkLen, Dreal);

    const size_t plane = (size_t)Hp * Wp;
    const float* Ib = Pi + (size_t)b * Dp * plane;
    const float* Jb = Pj + (size_t)b * Dp * plane;

    const int t  = threadIdx.x;
    const int hh = t >> 4, ww = t & 15;
    const bool valid = (w0 + ww) < Wreal;   // H exact-tiled at all scales

    const int wr  = t >> 2;
    const int wc4 = t & 3;
    const bool wact = t < NWT;
    const size_t rowoff = (size_t)(h0 + wr) * Wp + (w0 + 4 * wc4);

    auto load_slice = [&](int zp, float (&fi)[12], float (&fj)[12]) {
        if (wact) {
            const float* rI = Ib + (size_t)zp * plane + rowoff;
            const float* rJ = Jb + (size_t)zp * plane + rowoff;
            float4 a0 = *reinterpret_cast<const float4*>(rI);
            float4 a1 = *reinterpret_cast<const float4*>(rI + 4);
            float4 a2 = *reinterpret_cast<const float4*>(rI + 8);
            float4 b0 = *reinterpret_cast<const float4*>(rJ);
            float4 b1 = *reinterpret_cast<const float4*>(rJ + 4);
            float4 b2 = *reinterpret_cast<const float4*>(rJ + 8);
            fi[0]=a0.x; fi[1]=a0.y; fi[2]=a0.z; fi[3]=a0.w;
            fi[4]=a1.x; fi[5]=a1.y; fi[6]=a1.z; fi[7]=a1.w;
            fi[8]=a2.x; fi[9]=a2.y; fi[10]=a2.z; fi[11]=a2.w;
            fj[0]=b0.x; fj[1]=b0.y; fj[2]=b0.z; fj[3]=b0.w;
            fj[4]=b1.x; fj[5]=b1.y; fj[6]=b1.z; fj[7]=b1.w;
            fj[8]=b2.x; fj[9]=b2.y; fj[10]=b2.z; fj[11]=b2.w;
        }
    };

    float ring[WIN][5];
    float rs[5];
    #pragma unroll
    for (int s = 0; s < WIN; ++s)
        #pragma unroll
        for (int c = 0; c < 5; ++c) ring[s][c] = 0.f;
    #pragma unroll
    for (int c = 0; c < 5; ++c) rs[c] = 0.f;

    float ccsum = 0.f;

    float fiC[12], fjC[12], fiN[12], fjN[12];
    const int zend = z1 + RAD;
    load_slice(z0 - RAD + 4, fiC, fjC);       // prologue (padded z >= 0)

    for (int zb = z0 - RAD; zb < zend; zb += WIN) {
        #pragma unroll
        for (int ph = 0; ph < WIN; ++ph) {
            const int z = zb + ph;                 // uniform across block
            if (z < zend) {
                // ---- 1) prefetch slice z+1 (clamped; pads are zeros) ----
                const int zpn = min(z + 5, Dp - 1);
                load_slice(zpn, fiN, fjN);

                const int par = (z + 4) & 1;       // uniform parity
                float n0, n1, n2, n3, n4;
                // ---- 2) W phase: sliding 5-ch sums ----
                if (wact) {
                    float s0 = 0, s1 = 0, s2 = 0, s3 = 0, s4 = 0;
                    #pragma unroll
                    for (int k = 0; k < WIN; ++k) {
                        float a = fiC[OFF + k], bb = fjC[OFF + k];
                        s0 += a; s1 += bb;
                        s2 = fmaf(a, a, s2);
                        s3 = fmaf(bb, bb, s3);
                        s4 = fmaf(a, bb, s4);
                    }
                    float o0[4], o1[4], o2[4], o3[4], o4[4];
                    o0[0]=s0; o1[0]=s1; o2[0]=s2; o3[0]=s3; o4[0]=s4;
                    #pragma unroll
                    for (int m = 1; m < 4; ++m) {
                        float aL = fiC[OFF + m - 1],       bL = fjC[OFF + m - 1];
                        float aR = fiC[OFF + m - 1 + WIN], bR = fjC[OFF + m - 1 + WIN];
                        s0 += aR - aL;
                        s1 += bR - bL;
                        s2 = s2 + aR * aR - aL * aL;
                        s3 = s3 + bR * bR - bL * bL;
                        s4 = s4 + aR * bR - aL * bL;
                        o0[m]=s0; o1[m]=s1; o2[m]=s2; o3[m]=s3; o4[m]=s4;
                    }
                    #pragma unroll
                    for (int m = 0; m < 4; ++m) {
                        *reinterpret_cast<float4*>(&wb0123[par][wr * PSTR + 16 * wc4 + 4 * m]) =
                            make_float4(o0[m], o1[m], o2[m], o3[m]);
                    }
                    *reinterpret_cast<float4*>(&wb4[par][wr * QSTR + 4 * wc4]) =
                        make_float4(o4[0], o4[1], o4[2], o4[3]);
                }
                // ---- clobber-free barrier: vmcnt stays in flight ----
                __builtin_amdgcn_sched_barrier(0);
                asm volatile("s_waitcnt lgkmcnt(0)");
                __builtin_amdgcn_s_barrier();
                __builtin_amdgcn_sched_barrier(0);
                // ---- 3) H phase: 9 taps of (b128 + b32) ----
                {
                    float4 a4 = make_float4(0.f, 0.f, 0.f, 0.f);
                    float nn4 = 0.f;
                    #pragma unroll
                    for (int dh = 0; dh < WIN; ++dh) {
                        float4 v = *reinterpret_cast<const float4*>(
                            &wb0123[par][(hh + dh) * PSTR + 4 * ww]);
                        a4.x += v.x; a4.y += v.y; a4.z += v.z; a4.w += v.w;
                        nn4 += wb4[par][(hh + dh) * QSTR + ww];
                    }
                    n0 = a4.x; n1 = a4.y; n2 = a4.z; n3 = a4.w; n4 = nn4;
                }
                // ---- 4) ring update ----
                rs[0] += n0 - ring[ph][0]; ring[ph][0] = n0;
                rs[1] += n1 - ring[ph][1]; ring[ph][1] = n1;
                rs[2] += n2 - ring[ph][2]; ring[ph][2] = n2;
                rs[3] += n3 - ring[ph][3]; ring[ph][3] = n3;
                rs[4] += n4 - ring[ph][4]; ring[ph][4] = n4;

                // ---- 5) emit cc for output slice zo = z - RAD ----
                const int zo = z - RAD;
                if (valid && zo >= z0) {
                    float muI = rs[0] * invV;
                    float muJ = rs[1] * invV;
                    float sII = rs[2] * invV - muI * muI;
                    float sJJ = rs[3] * invV - muJ * muJ;
                    float s12 = rs[4] * invV - muI * muJ;
                    float cc = (s12 * s12) / fmaxf(sII * sJJ, NCC_EPS);
                    ccsum += cc;
                }
                // ---- 6) rotate prefetch regs (vmcnt waits land here) ----
                #pragma unroll
                for (int e = 0; e < 12; ++e) { fiC[e] = fiN[e]; fjC[e] = fjN[e]; }
            }
        }
    }

    for (int off = 32; off > 0; off >>= 1)
        ccsum += __shfl_down(ccsum, off);
    const int wid = t >> 6, lane = t & 63;
    if (lane == 0) red[wid] = ccsum;
    __syncthreads();
    if (t == 0) {
        float s = red[0] + red[1] + red[2] + red[3];
        atomicAdd(acc, (double)s);
    }
}

// Pad-copy scale-0 inputs into [Dp][Hp][Wp] with zero borders (both arrays).
__global__ void pad_kernel(const float* __restrict__ inA, const float* __restrict__ inB,
                           float* __restrict__ outA, float* __restrict__ outB,
                           int D, int H, int W, int Dp, int Hp, int Wp, int nchunks)
{
    int idx = blockIdx.x * 256 + threadIdx.x;
    if (idx >= 2 * nchunks) return;
    const bool isB = idx >= nchunks;
    int k = isB ? idx - nchunks : idx;
    const float* in = isB ? inB : inA;
    float* out = isB ? outB : outA;
    const int WC = Wp / 4;
    int wc = k % WC; int tmp = k / WC;
    int hp = tmp % Hp; tmp /= Hp;
    int zp = tmp % Dp; int b = tmp / Dp;
    int z = zp - 4, h = hp - 4, w0 = 4 * wc - 4;
    float4 v = make_float4(0.f, 0.f, 0.f, 0.f);
    if (z >= 0 && z < D && h >= 0 && h < H && w0 >= 0 && w0 + 4 <= W)
        v = *reinterpret_cast<const float4*>(in + ((size_t)(b * D + z) * H + h) * W + w0);
    *reinterpret_cast<float4*>(out + ((size_t)(b * Dp + zp) * Hp + hp) * Wp + 4 * wc) = v;
}

// avg_pool3d k=3 s=2 pad=1 count_include_pad=False; padded in -> padded out.
__global__ void pool_pad_kernel(const float* __restrict__ inA, const float* __restrict__ inB,
                                float* __restrict__ outA, float* __restrict__ outB,
                                int D, int H, int W, int iDp, int iHp, int iWp,
                                int oD, int oH, int oW, int oDp, int oHp, int oWp,
                                int total)
{
    int idx0 = blockIdx.x * 256 + threadIdx.x;
    if (idx0 >= 2 * total) return;
    const bool isB = idx0 >= total;
    int idx = isB ? idx0 - total : idx0;
    const float* in = isB ? inB : inA;
    float* out = isB ? outB : outA;

    int ow = idx % oW; int tmp = idx / oW;
    int oh = tmp % oH; tmp /= oH;
    int od = tmp % oD; int b = tmp / oD;

    const size_t ip = (size_t)iHp * iWp;
    const float* ib = in + (size_t)b * iDp * ip;
    float s = 0.f;
    #pragma unroll
    for (int dd = 0; dd < 3; ++dd)
        #pragma unroll
        for (int dh = 0; dh < 3; ++dh) {
            const float* r = ib + (size_t)(2 * od + 3 + dd) * ip
                                + (size_t)(2 * oh + 3 + dh) * iWp + (2 * ow + 3);
            s += r[0] + r[1] + r[2];
        }
    int dlo = max(2 * od - 1, 0), dhi = min(2 * od + 2, D);
    int hlo = max(2 * oh - 1, 0), hhi = min(2 * oh + 2, H);
    int wlo = max(2 * ow - 1, 0), whi = min(2 * ow + 2, W);
    int cnt = (dhi - dlo) * (hhi - hlo) * (whi - wlo);
    out[((size_t)(b * oDp + od + 4) * oHp + (oh + 4)) * oWp + (ow + 4)] = s / (float)cnt;
}

// ===========================================================================
// FALLBACK PATH (small workspace): bounded kernel, verified passing.
// ===========================================================================
template<int WIN>
__global__ __launch_bounds__(256)
void ncc_scale_kernel(const float* __restrict__ I, const float* __restrict__ J,
                      int D, int H, int W,
                      int tilesH, int tilesW, int chunksD, int chunkLen,
                      double* __restrict__ acc)
{
    constexpr int RAD  = WIN / 2;
    constexpr int TH = 16, TW = 16;
    constexpr int WROWS = TH + 2 * RAD;
    constexpr int PSTR = 68;
    constexpr int QSTR = 24;
    constexpr int OFF  = 4 - RAD;
    constexpr int NWT  = WROWS * 4;
    constexpr float invV = 1.0f / (float)(WIN * WIN * WIN);

    __shared__ __align__(16) float wb0123[2][WROWS * PSTR];
    __shared__ __align__(16) float wb4[2][WROWS * QSTR];
    __shared__ float red[4];

    int bid = blockIdx.x;
    int tw = bid % tilesW; bid /= tilesW;
    int th = bid % tilesH; bid /= tilesH;
    int cd = bid % chunksD; bid /= chunksD;
    int b  = bid;

    const int h0 = th * TH, w0 = tw * TW;
    const int z0 = cd * chunkLen;
    const int z1 = min(z0 + chunkLen, D);

    const size_t plane = (size_t)H * W;
    const float* Ib = I + (size_t)b * D * plane;
    const float* Jb = J + (size_t)b * D * plane;

    const int t  = threadIdx.x;
    const int hh = t >> 4, ww = t & 15;
    const int gh = h0 + hh, gw = w0 + ww;
    const bool valid = (gh < H) && (gw < W);

    const int wr  = t >> 2;
    const int wc4 = t & 3;
    const bool wact = t < NWT;
    const int wbase = w0 + 4 * wc4 - 4;
    const int wghr  = h0 + wr - RAD;

    auto load_slice = [&](int z, float (&fi)[12], float (&fj)[12]) {
        const bool zok = (z >= 0) && (z < D);
        if (zok && wact && wghr >= 0 && wghr < H) {
            const float* rowI = Ib + (size_t)z * plane + (size_t)wghr * W;
            const float* rowJ = Jb + (size_t)z * plane + (size_t)wghr * W;
            if (wbase >= 0 && wbase + 12 <= W) {
                float4 a0 = *reinterpret_cast<const float4*>(rowI + wbase);
                float4 a1 = *reinterpret_cast<const float4*>(rowI + wbase + 4);
                float4 a2 = *reinterpret_cast<const float4*>(rowI + wbase + 8);
                float4 b0 = *reinterpret_cast<const float4*>(rowJ + wbase);
                float4 b1 = *reinterpret_cast<const float4*>(rowJ + wbase + 4);
                float4 b2 = *reinterpret_cast<const float4*>(rowJ + wbase + 8);
                fi[0]=a0.x; fi[1]=a0.y; fi[2]=a0.z; fi[3]=a0.w;
                fi[4]=a1.x; fi[5]=a1.y; fi[6]=a1.z; fi[7]=a1.w;
                fi[8]=a2.x; fi[9]=a2.y; fi[10]=a2.z; fi[11]=a2.w;
                fj[0]=b0.x; fj[1]=b0.y; fj[2]=b0.z; fj[3]=b0.w;
                fj[4]=b1.x; fj[5]=b1.y; fj[6]=b1.z; fj[7]=b1.w;
                fj[8]=b2.x; fj[9]=b2.y; fj[10]=b2.z; fj[11]=b2.w;
            } else {
                #pragma unroll
                for (int e = 0; e < 12; ++e) {
                    int cg = wbase + e;
                    bool ok = (cg >= 0) && (cg < W);
                    fi[e] = ok ? rowI[cg] : 0.f;
                    fj[e] = ok ? rowJ[cg] : 0.f;
                }
            }
        } else {
            #pragma unroll
            for (int e = 0; e < 12; ++e) { fi[e] = 0.f; fj[e] = 0.f; }
        }
    };

    float ring[WIN][5];
    float rs[5];
    #pragma unroll
    for (int s = 0; s < WIN; ++s)
        #pragma unroll
        for (int c = 0; c < 5; ++c) ring[s][c] = 0.f;
    #pragma unroll
    for (int c = 0; c < 5; ++c) rs[c] = 0.f;

    float ccsum = 0.f;

    float fiC[12], fjC[12], fiN[12], fjN[12];
    const int zend = z1 + RAD;
    load_slice(z0 - RAD, fiC, fjC);

    for (int zb = z0 - RAD; zb < zend; zb += WIN) {
        #pragma unroll
        for (int ph = 0; ph < WIN; ++ph) {
            const int z = zb + ph;
            if (z < zend) {
                const bool zin = (z >= 0) && (z < D);
                load_slice((z + 1 < zend) ? z + 1 : -1, fiN, fjN);
                float n0 = 0, n1 = 0, n2 = 0, n3 = 0, n4 = 0;
                if (zin) {
                    const int par = (z + 64) & 1;
                    if (wact) {
                        float s0 = 0, s1 = 0, s2 = 0, s3 = 0, s4 = 0;
                        #pragma unroll
                        for (int k = 0; k < WIN; ++k) {
                            float a = fiC[OFF + k], bb = fjC[OFF + k];
                            s0 += a; s1 += bb;
                            s2 = fmaf(a, a, s2);
                            s3 = fmaf(bb, bb, s3);
                            s4 = fmaf(a, bb, s4);
                        }
                        float o0[4], o1[4], o2[4], o3[4], o4[4];
                        o0[0]=s0; o1[0]=s1; o2[0]=s2; o3[0]=s3; o4[0]=s4;
                        #pragma unroll
                        for (int m = 1; m < 4; ++m) {
                            float aL = fiC[OFF + m - 1],       bL = fjC[OFF + m - 1];
                            float aR = fiC[OFF + m - 1 + WIN], bR = fjC[OFF + m - 1 + WIN];
                            s0 += aR - aL;
                            s1 += bR - bL;
                            s2 = s2 + aR * aR - aL * aL;
                            s3 = s3 + bR * bR - bL * bL;
                            s4 = s4 + aR * bR - aL * bL;
                            o0[m]=s0; o1[m]=s1; o2[m]=s2; o3[m]=s3; o4[m]=s4;
                        }
                        #pragma unroll
                        for (int m = 0; m < 4; ++m) {
                            *reinterpret_cast<float4*>(&wb0123[par][wr * PSTR + 16 * wc4 + 4 * m]) =
                                make_float4(o0[m], o1[m], o2[m], o3[m]);
                        }
                        *reinterpret_cast<float4*>(&wb4[par][wr * QSTR + 4 * wc4]) =
                            make_float4(o4[0], o4[1], o4[2], o4[3]);
                    }
                    __syncthreads();
                    float4 a4 = make_float4(0.f, 0.f, 0.f, 0.f);
                    #pragma unroll
                    for (int dh = 0; dh < WIN; ++dh) {
                        float4 v = *reinterpret_cast<const float4*>(
                            &wb0123[par][(hh + dh) * PSTR + 4 * ww]);
                        a4.x += v.x; a4.y += v.y; a4.z += v.z; a4.w += v.w;
                        n4 += wb4[par][(hh + dh) * QSTR + ww];
                    }
                    n0 = a4.x; n1 = a4.y; n2 = a4.z; n3 = a4.w;
                }
                rs[0] += n0 - ring[ph][0]; ring[ph][0] = n0;
                rs[1] += n1 - ring[ph][1]; ring[ph][1] = n1;
                rs[2] += n2 - ring[ph][2]; ring[ph][2] = n2;
                rs[3] += n3 - ring[ph][3]; ring[ph][3] = n3;
                rs[4] += n4 - ring[ph][4]; ring[ph][4] = n4;

                const int zo = z - RAD;
                if (valid && zo >= z0) {
                    float muI = rs[0] * invV;
                    float muJ = rs[1] * invV;
                    float sII = rs[2] * invV - muI * muI;
                    float sJJ = rs[3] * invV - muJ * muJ;
                    float s12 = rs[4] * invV - muI * muJ;
                    float cc = (s12 * s12) / fmaxf(sII * sJJ, NCC_EPS);
                    ccsum += cc;
                }
                #pragma unroll
                for (int e = 0; e < 12; ++e) { fiC[e] = fiN[e]; fjC[e] = fjN[e]; }
            }
        }
    }

    for (int off = 32; off > 0; off >>= 1)
        ccsum += __shfl_down(ccsum, off);
    const int wid = t >> 6, lane = t & 63;
    if (lane == 0) red[wid] = ccsum;
    __syncthreads();
    if (t == 0) {
        float s = red[0] + red[1] + red[2] + red[3];
        atomicAdd(acc, (double)s);
    }
}

__global__ void pool_kernel2(const float* __restrict__ inA, const float* __restrict__ inB,
                             float* __restrict__ outA, float* __restrict__ outB,
                             int D, int H, int W, int oD, int oH, int oW, int total)
{
    int idx0 = blockIdx.x * 256 + threadIdx.x;
    if (idx0 >= 2 * total) return;
    const bool isB = idx0 >= total;
    int idx = isB ? idx0 - total : idx0;
    const float* in = isB ? inB : inA;
    float* out = isB ? outB : outA;

    int ow = idx % oW; int tmp = idx / oW;
    int oh = tmp % oH; tmp /= oH;
    int od = tmp % oD; int b = tmp / oD;

    int dlo = max(2 * od - 1, 0), dhi = min(2 * od + 2, D);
    int hlo = max(2 * oh - 1, 0), hhi = min(2 * oh + 2, H);
    int wlo = max(2 * ow - 1, 0), whi = min(2 * ow + 2, W);

    const float* ib = in + (size_t)b * D * H * W;
    float s = 0.f;
    for (int d = dlo; d < dhi; ++d)
        for (int h = hlo; h < hhi; ++h)
            for (int w = wlo; w < whi; ++w)
                s += ib[((size_t)d * H + h) * W + w];
    int cnt = (dhi - dlo) * (hhi - hlo) * (whi - wlo);
    out[idx] = s / (float)cnt;
}

__global__ void finalize_kernel(const double* __restrict__ acc, float* __restrict__ out)
{
    double m = acc[0] / 9830400.0 + acc[1] / 1228800.0 + acc[2] / 153600.0;
    out[0] = (float)(-m / 3.0);
}

extern "C" void kernel_launch(void* const* d_in, const int* in_sizes, int n_in,
                              void* d_out, int out_size, void* d_ws, size_t ws_size,
                              hipStream_t stream)
{
    const float* I0 = (const float*)d_in[0];
    const float* J0 = (const float*)d_in[1];
    float* out = (float*)d_out;

    char* ws = (char*)d_ws;
    double* acc = (double*)ws;
    hipMemsetAsync(acc, 0, 3 * sizeof(double), stream);

    // padded sizes (floats)
    const size_t P0SZ = (size_t)2 * 168 * 200 * 168;   // 11,289,600
    const size_t P1SZ = (size_t)2 * 88 * 104 * 88;     //  1,610,752
    const size_t P2SZ = (size_t)2 * 48 * 56 * 56;      //    301,056
    const size_t need_pad = 256 + (2 * P0SZ + 2 * P1SZ + 2 * P2SZ) * sizeof(float);

    if (ws_size >= need_pad) {
        // ---------------- PADDED PATH ----------------
        float* P0I = (float*)(ws + 256);
        float* P0J = P0I + P0SZ;
        float* P1I = P0J + P0SZ;
        float* P1J = P1I + P1SZ;
        float* P2I = P1J + P1SZ;
        float* P2J = P2I + P2SZ;

        hipMemsetAsync(P1I, 0, (2 * P1SZ + 2 * P2SZ) * sizeof(float), stream);

        // pad scale-0 inputs
        {
            int nchunks = (int)(P0SZ / 4);
            int blocks = (2 * nchunks + 255) / 256;
            pad_kernel<<<blocks, 256, 0, stream>>>(I0, J0, P0I, P0J,
                                                   160, 192, 160, 168, 200, 168, nchunks);
        }
        // scale 0: win=9 -- 1440 blocks = 5.6/CU (6-block residency capacity)
        ncc_pad_kernel<9><<<2 * 12 * 10 * 6, 256, 0, stream>>>(
            P0I, P0J, 168, 200, 168, 160, 160, 12, 10, 6, 27, acc + 0);
        // pool 0 -> 1
        {
            int total = 2 * 80 * 96 * 80;
            int blocks = (2 * total + 255) / 256;
            pool_pad_kernel<<<blocks, 256, 0, stream>>>(P0I, P0J, P1I, P1J,
                                                        160, 192, 160, 168, 200, 168,
                                                        80, 96, 80, 88, 104, 88, total);
        }
        // scale 1: win=7 -- 600 blocks (was 240: <1/CU)
        ncc_pad_kernel<7><<<2 * 6 * 5 * 10, 256, 0, stream>>>(
            P1I, P1J, 88, 104, 88, 80, 80, 6, 5, 10, 8, acc + 1);
        // pool 1 -> 2
        {
            int total = 2 * 40 * 48 * 40;
            int blocks = (2 * total + 255) / 256;
            pool_pad_kernel<<<blocks, 256, 0, stream>>>(P1I, P1J, P2I, P2J,
                                                        80, 96, 80, 88, 104, 88,
                                                        40, 48, 40, 48, 56, 56, total);
        }
        // scale 2: win=5
        ncc_pad_kernel<5><<<2 * 3 * 3 * 5, 256, 0, stream>>>(
            P2I, P2J, 48, 56, 56, 40, 40, 3, 3, 5, 8, acc + 2);
    } else {
        // ---------------- FALLBACK (bounded path) ----------------
        float* I1 = (float*)(ws + 256);
        float* J1 = I1 + (size_t)2 * 80 * 96 * 80;
        float* I2 = J1 + (size_t)2 * 80 * 96 * 80;
        float* J2 = I2 + (size_t)2 * 40 * 48 * 40;

        ncc_scale_kernel<9><<<2 * 12 * 10 * 6, 256, 0, stream>>>(
            I0, J0, 160, 192, 160, 12, 10, 6, 27, acc + 0);
        {
            int total = 2 * 80 * 96 * 80;
            int blocks = (2 * total + 255) / 256;
            pool_kernel2<<<blocks, 256, 0, stream>>>(I0, J0, I1, J1,
                                                     160, 192, 160, 80, 96, 80, total);
        }
        ncc_scale_kernel<7><<<2 * 6 * 5 * 10, 256, 0, stream>>>(
            I1, J1, 80, 96, 80, 6, 5, 10, 8, acc + 1);
        {
            int total = 2 * 40 * 48 * 40;
            int blocks = (2 * total + 255) / 256;
            pool_kernel2<<<blocks, 256, 0, stream>>>(I1, J1, I2, J2,
                                                     80, 96, 80, 40, 48, 40, total);
        }
        ncc_scale_kernel<5><<<2 * 3 * 3 * 14, 256, 0, stream>>>(
            I2, J2, 40, 48, 40, 3, 3, 14, 3, acc + 2);
    }

    finalize_kernel<<<1, 1, 0, stream>>>(acc, out);
}